// Round 5
// baseline (1421.106 us; speedup 1.0000x reference)
//
#include <hip/hip_runtime.h>
#include <math.h>

#define N_NODES 50000
#define N_EDGES 800000
#define IN_C 16
#define HID_C 16
#define OUT_C 10
#define N_GRAPHS 500
#define EDGE_DIM 3
#define MLP_HID 25
#define BN_EPS 1e-5f

// ---------------- small prep ----------------

// block 0: fold BN into edge-MLP layer-1 -> AC[k][4]={A0,A1,A2,C}
// all blocks: goff[g] = lower_bound(batch, g) (batch sorted)
__global__ __launch_bounds__(256) void prep_graph_kernel(
    const float* __restrict__ W1a, const float* __restrict__ b1a,
    const float* __restrict__ g1, const float* __restrict__ bt1,
    const float* __restrict__ m1, const float* __restrict__ v1,
    const float* __restrict__ W2a, const float* __restrict__ b2a,
    const float* __restrict__ g2, const float* __restrict__ bt2,
    const float* __restrict__ m2, const float* __restrict__ v2,
    const int* __restrict__ batch,
    float* __restrict__ AC1, float* __restrict__ AC2,
    int* __restrict__ goff)
{
    int t = threadIdx.x;
    if (blockIdx.x == 0) {
        if (t < MLP_HID) {
            int k = t;
            float sc = g1[k] / sqrtf(v1[k] + BN_EPS);
            AC1[k*4+0] = sc * W1a[0*MLP_HID+k];
            AC1[k*4+1] = sc * W1a[1*MLP_HID+k];
            AC1[k*4+2] = sc * W1a[2*MLP_HID+k];
            AC1[k*4+3] = sc * (b1a[k] - m1[k]) + bt1[k];
        } else if (t >= 32 && t < 32 + MLP_HID) {
            int k = t - 32;
            float sc = g2[k] / sqrtf(v2[k] + BN_EPS);
            AC2[k*4+0] = sc * W2a[0*MLP_HID+k];
            AC2[k*4+1] = sc * W2a[1*MLP_HID+k];
            AC2[k*4+2] = sc * W2a[2*MLP_HID+k];
            AC2[k*4+3] = sc * (b2a[k] - m2[k]) + bt2[k];
        }
    }
    int g = blockIdx.x * blockDim.x + t;
    if (g <= N_GRAPHS) {
        int lo = 0, hi = N_NODES;
        while (lo < hi) {
            int mid = (lo + hi) >> 1;
            if (batch[mid] < g) lo = mid + 1; else hi = mid;
        }
        goff[g] = lo;
    }
}

// ---------------- CSR build (one atomic pass) ----------------

// rank[e] = arrival rank of edge e within its dst bucket; cnt ends as degree.
__global__ __launch_bounds__(256) void rank_kernel(const int* __restrict__ dst,
                                                   int* __restrict__ cnt,
                                                   int* __restrict__ rank) {
    int e = blockIdx.x * blockDim.x + threadIdx.x;
    if (e < N_EDGES) rank[e] = atomicAdd(&cnt[dst[e]], 1);
}

// single block of 1024: exclusive scan of cnt -> off[0..N]
__global__ __launch_bounds__(1024) void scan_kernel(const int* __restrict__ deg,
                                                    int* __restrict__ off) {
    __shared__ int lds[1024];
    const int t = threadIdx.x;
    const int CHUNK = (N_NODES + 1023) / 1024;  // 49
    int lo = t * CHUNK;
    int hi = lo + CHUNK; if (hi > N_NODES) hi = N_NODES;
    int s = 0;
    for (int r = lo; r < hi; ++r) s += deg[r];
    lds[t] = s;
    __syncthreads();
    for (int d = 1; d < 1024; d <<= 1) {
        int v = (t >= d) ? lds[t - d] : 0;
        __syncthreads();
        lds[t] += v;
        __syncthreads();
    }
    int run = (t > 0) ? lds[t - 1] : 0;
    for (int r = lo; r < hi; ++r) {
        off[r] = run;
        run += deg[r];
    }
    if (t == 1023) off[N_NODES] = lds[1023];
}

// ---------------- hot path ----------------

// k-SPLIT edge kernel: block = 256 threads = 4 waves = 2 groups of 64 edges.
// Waves (2g, 2g+1) both process edge group g: wave half=0 does k in [0,13),
// half=1 does k in [13,25) + the bias term. Doubles wave-level parallelism
// (25k waves vs 12.5k) so the SQC/L2 scalar-load latency of the Wb stream is
// hidden by more resident waves; each wave streams only ~13 KB of weights.
// Partials combined via LDS (+1 pad -> conflict-free), half=1 stores the row
// to CSR slot p = off[dst]+rank (no atomics in this kernel).
__global__ __launch_bounds__(256) void edge_ks_kernel(
    const float* __restrict__ xin,
    const int* __restrict__ src, const int* __restrict__ dst,
    const int* __restrict__ rank, const int* __restrict__ off,
    const float* __restrict__ eattr,
    const float* __restrict__ AC,
    const float* __restrict__ Wb, const float* __restrict__ bb,
    float* __restrict__ msg_buf)
{
    __shared__ float part[128][HID_C + 1];  // +1 pad: lane stride 17 -> no bank conflict
    const int tid  = threadIdx.x;
    const int wave = tid >> 6;
    const int lane = tid & 63;
    const int grp  = wave >> 1;
    const int half = wave & 1;
    const int eloc = grp * 64 + lane;          // 0..127
    const int e    = blockIdx.x * 128 + eloc;  // N_EDGES = 6250*128 exactly

    const int s = src[e];
    const float a0 = eattr[e*3+0], a1 = eattr[e*3+1], a2 = eattr[e*3+2];

    int p = 0;
    if (half) p = off[dst[e]] + rank[e];  // issued early; needed only at store

    float xs[IN_C];
    {
        const float4* xp = (const float4*)(xin + (size_t)s * IN_C);
        float4 q0 = xp[0], q1 = xp[1], q2 = xp[2], q3 = xp[3];
        xs[0]=q0.x; xs[1]=q0.y; xs[2]=q0.z; xs[3]=q0.w;
        xs[4]=q1.x; xs[5]=q1.y; xs[6]=q1.z; xs[7]=q1.w;
        xs[8]=q2.x; xs[9]=q2.y; xs[10]=q2.z; xs[11]=q2.w;
        xs[12]=q3.x; xs[13]=q3.y; xs[14]=q3.z; xs[15]=q3.w;
    }

    float msg[HID_C];
    #pragma unroll
    for (int o = 0; o < HID_C; ++o) msg[o] = 0.f;

    if (half) {
        // bias of the second linear (part of w) -> charged to the lighter half
        #pragma unroll
        for (int i = 0; i < IN_C; ++i) {
            #pragma unroll
            for (int o = 0; o < HID_C; ++o)
                msg[o] = fmaf(xs[i], bb[i*HID_C+o], msg[o]);
        }
    }

    const int k0 = half ? 13 : 0;
    const int k1 = half ? MLP_HID : 13;
    #pragma unroll 1
    for (int k = k0; k < k1; ++k) {
        float A0 = AC[k*4+0], A1 = AC[k*4+1], A2 = AC[k*4+2], C = AC[k*4+3];
        float hk = fmaxf(fmaf(a2, A2, fmaf(a1, A1, fmaf(a0, A0, C))), 0.f);
        const float* Wrow = Wb + k * (IN_C*HID_C);
        #pragma unroll
        for (int i = 0; i < IN_C; ++i) {
            float ai = hk * xs[i];
            #pragma unroll
            for (int o = 0; o < HID_C; ++o)
                msg[o] = fmaf(ai, Wrow[i*HID_C+o], msg[o]);
        }
    }

    if (!half) {
        #pragma unroll
        for (int o = 0; o < HID_C; ++o) part[eloc][o] = msg[o];
    }
    __syncthreads();
    if (half) {
        #pragma unroll
        for (int o = 0; o < HID_C; ++o) msg[o] += part[eloc][o];
        float4* mp = (float4*)(msg_buf + (size_t)p * HID_C);
        mp[0] = make_float4(msg[0], msg[1], msg[2], msg[3]);
        mp[1] = make_float4(msg[4], msg[5], msg[6], msg[7]);
        mp[2] = make_float4(msg[8], msg[9], msg[10], msg[11]);
        mp[3] = make_float4(msg[12], msg[13], msg[14], msg[15]);
    }
}

// 16 threads per node (lane = out channel). Segment-sum msg_buf rows
// [off[n], off[n+1]) -> mean -> + x@root + bias -> ELU.
__global__ __launch_bounds__(256) void node_gather_kernel(
    const float* __restrict__ xin, const float* __restrict__ msg_buf,
    const int* __restrict__ off,
    const float* __restrict__ root, const float* __restrict__ bias,
    float* __restrict__ xout)
{
    int t = blockIdx.x * blockDim.x + threadIdx.x;
    int n = t >> 4;
    int o = t & 15;
    if (n >= N_NODES) return;
    int lo = off[n], hi = off[n+1];
    float inv = 1.f / fmaxf((float)(hi - lo), 1.f);

    float s0 = 0.f, s1 = 0.f, s2 = 0.f, s3 = 0.f;
    int r = lo;
    for (; r + 4 <= hi; r += 4) {
        s0 += msg_buf[(size_t)r     * HID_C + o];
        s1 += msg_buf[(size_t)(r+1) * HID_C + o];
        s2 += msg_buf[(size_t)(r+2) * HID_C + o];
        s3 += msg_buf[(size_t)(r+3) * HID_C + o];
    }
    for (; r < hi; ++r) s0 += msg_buf[(size_t)r * HID_C + o];
    float s = (s0 + s1) + (s2 + s3);

    float acc = fmaf(s, inv, bias[o]);
    const float* xr = xin + (size_t)n * IN_C;
    #pragma unroll
    for (int i = 0; i < IN_C; ++i)
        acc = fmaf(xr[i], root[i*HID_C+o], acc);
    xout[(size_t)n*HID_C + o] = acc > 0.f ? acc : (expf(acc) - 1.f);
}

// fused: global mean pool (batch sorted -> contiguous segments) + final linear
__global__ __launch_bounds__(64) void pool_final_kernel(
    const float* __restrict__ xin, const int* __restrict__ goff,
    const float* __restrict__ fcW, const float* __restrict__ fcb,
    float* __restrict__ out)
{
    __shared__ float part[4][HID_C];
    __shared__ float pooled[HID_C];
    int g = blockIdx.x;
    int t = threadIdx.x;
    int c = t & 15, sub = t >> 4;
    int lo = goff[g], hi = goff[g+1];
    float s = 0.f;
    for (int n = lo + sub; n < hi; n += 4)
        s += xin[(size_t)n*HID_C + c];
    part[sub][c] = s;
    __syncthreads();
    if (t < HID_C) {
        float v = (part[0][t] + part[1][t] + part[2][t] + part[3][t])
                  / fmaxf((float)(hi - lo), 1.f);
        pooled[t] = v;
    }
    __syncthreads();
    if (t < OUT_C) {
        float acc = fcb[t];
        #pragma unroll
        for (int i = 0; i < HID_C; ++i)
            acc = fmaf(pooled[i], fcW[i*OUT_C+t], acc);
        out[g*OUT_C + t] = acc;
    }
}

// ---------------- launch ----------------

extern "C" void kernel_launch(void* const* d_in, const int* in_sizes, int n_in,
                              void* d_out, int out_size, void* d_ws, size_t ws_size,
                              hipStream_t stream)
{
    const float* x     = (const float*)d_in[0];
    const int*   ei    = (const int*)d_in[1];
    const float* eattr = (const float*)d_in[2];
    const int*   batch = (const int*)d_in[3];
    const float* W1a   = (const float*)d_in[4];
    const float* b1a   = (const float*)d_in[5];
    const float* g1    = (const float*)d_in[6];
    const float* bt1   = (const float*)d_in[7];
    const float* m1    = (const float*)d_in[8];
    const float* v1    = (const float*)d_in[9];
    const float* W1b   = (const float*)d_in[10];
    const float* b1b   = (const float*)d_in[11];
    const float* root1 = (const float*)d_in[12];
    const float* bias1 = (const float*)d_in[13];
    const float* W2a   = (const float*)d_in[14];
    const float* b2a   = (const float*)d_in[15];
    const float* g2    = (const float*)d_in[16];
    const float* bt2   = (const float*)d_in[17];
    const float* m2    = (const float*)d_in[18];
    const float* v2    = (const float*)d_in[19];
    const float* W2b   = (const float*)d_in[20];
    const float* b2b   = (const float*)d_in[21];
    const float* root2 = (const float*)d_in[22];
    const float* bias2 = (const float*)d_in[23];
    const float* fcW   = (const float*)d_in[24];
    const float* fcb   = (const float*)d_in[25];

    const int* src = ei;
    const int* dst = ei + N_EDGES;

    float* ws   = (float*)d_ws;
    float* MSG  = ws;                          // 12,800,000 f
    float* X1   = ws + 12800000;               //    800,000 f
    float* X2   = ws + 13600000;               //    800,000 f
    int*   RANK = (int*)(ws + 14400000);       //    800,000 i
    int*   CNT  = (int*)(ws + 15200000);       //     50,000 i
    int*   OFF  = (int*)(ws + 15250000);       //     50,001 i (+pad)
    int*   GOFF = (int*)(ws + 15300096);       //        501 i (+pad)
    float* AC1  = ws + 15300608;               //        128 f
    float* AC2  = ws + 15300736;               //        128 f
    // total 15,300,864 f = 61.2 MB (R2 used 61.4 MB successfully)

    hipMemsetAsync(CNT, 0, N_NODES * sizeof(int), stream);
    prep_graph_kernel<<<3, 256, 0, stream>>>(W1a, b1a, g1, bt1, m1, v1,
                                             W2a, b2a, g2, bt2, m2, v2,
                                             batch, AC1, AC2, GOFF);
    rank_kernel<<<N_EDGES/256, 256, 0, stream>>>(dst, CNT, RANK);
    scan_kernel<<<1, 1024, 0, stream>>>(CNT, OFF);

    edge_ks_kernel<<<N_EDGES/128, 256, 0, stream>>>(x, src, dst, RANK, OFF,
                                                    eattr, AC1, W1b, b1b, MSG);
    node_gather_kernel<<<(N_NODES*16+255)/256, 256, 0, stream>>>(x, MSG, OFF,
                                                                 root1, bias1, X1);

    edge_ks_kernel<<<N_EDGES/128, 256, 0, stream>>>(X1, src, dst, RANK, OFF,
                                                    eattr, AC2, W2b, b2b, MSG);
    node_gather_kernel<<<(N_NODES*16+255)/256, 256, 0, stream>>>(X1, MSG, OFF,
                                                                 root2, bias2, X2);

    pool_final_kernel<<<N_GRAPHS, 64, 0, stream>>>(X2, GOFF, fcW, fcb, (float*)d_out);
}

// Round 6
// 476.843 us; speedup vs baseline: 2.9802x; 2.9802x over previous
//
#include <hip/hip_runtime.h>
#include <math.h>

#define N_NODES 50000
#define N_EDGES 800000
#define IN_C 16
#define HID_C 16
#define OUT_C 10
#define N_GRAPHS 500
#define EDGE_DIM 3
#define MLP_HID 25
#define BN_EPS 1e-5f

// ---------------- small prep ----------------

// block 0: fold BN into edge-MLP layer-1 -> AC[k][4]={A0,A1,A2,C}
// all blocks: goff[g] = lower_bound(batch, g) (batch sorted)
__global__ __launch_bounds__(256) void prep_graph_kernel(
    const float* __restrict__ W1a, const float* __restrict__ b1a,
    const float* __restrict__ g1, const float* __restrict__ bt1,
    const float* __restrict__ m1, const float* __restrict__ v1,
    const float* __restrict__ W2a, const float* __restrict__ b2a,
    const float* __restrict__ g2, const float* __restrict__ bt2,
    const float* __restrict__ m2, const float* __restrict__ v2,
    const int* __restrict__ batch,
    float* __restrict__ AC1, float* __restrict__ AC2,
    int* __restrict__ goff)
{
    int t = threadIdx.x;
    if (blockIdx.x == 0) {
        if (t < MLP_HID) {
            int k = t;
            float sc = g1[k] / sqrtf(v1[k] + BN_EPS);
            AC1[k*4+0] = sc * W1a[0*MLP_HID+k];
            AC1[k*4+1] = sc * W1a[1*MLP_HID+k];
            AC1[k*4+2] = sc * W1a[2*MLP_HID+k];
            AC1[k*4+3] = sc * (b1a[k] - m1[k]) + bt1[k];
        } else if (t >= 32 && t < 32 + MLP_HID) {
            int k = t - 32;
            float sc = g2[k] / sqrtf(v2[k] + BN_EPS);
            AC2[k*4+0] = sc * W2a[0*MLP_HID+k];
            AC2[k*4+1] = sc * W2a[1*MLP_HID+k];
            AC2[k*4+2] = sc * W2a[2*MLP_HID+k];
            AC2[k*4+3] = sc * (b2a[k] - m2[k]) + bt2[k];
        }
    }
    int g = blockIdx.x * blockDim.x + t;
    if (g <= N_GRAPHS) {
        int lo = 0, hi = N_NODES;
        while (lo < hi) {
            int mid = (lo + hi) >> 1;
            if (batch[mid] < g) lo = mid + 1; else hi = mid;
        }
        goff[g] = lo;
    }
}

// ---------------- CSR build (one atomic pass) ----------------

// rank[e] = arrival rank of edge e within its dst bucket; cnt ends as degree.
__global__ __launch_bounds__(256) void rank_kernel(const int* __restrict__ dst,
                                                   int* __restrict__ cnt,
                                                   int* __restrict__ rank) {
    int e = blockIdx.x * blockDim.x + threadIdx.x;
    if (e < N_EDGES) rank[e] = atomicAdd(&cnt[dst[e]], 1);
}

// single block of 1024: exclusive scan of cnt -> off[0..N]
__global__ __launch_bounds__(1024) void scan_kernel(const int* __restrict__ deg,
                                                    int* __restrict__ off) {
    __shared__ int lds[1024];
    const int t = threadIdx.x;
    const int CHUNK = (N_NODES + 1023) / 1024;  // 49
    int lo = t * CHUNK;
    int hi = lo + CHUNK; if (hi > N_NODES) hi = N_NODES;
    int s = 0;
    for (int r = lo; r < hi; ++r) s += deg[r];
    lds[t] = s;
    __syncthreads();
    for (int d = 1; d < 1024; d <<= 1) {
        int v = (t >= d) ? lds[t - d] : 0;
        __syncthreads();
        lds[t] += v;
        __syncthreads();
    }
    int run = (t > 0) ? lds[t - 1] : 0;
    for (int r = lo; r < hi; ++r) {
        off[r] = run;
        run += deg[r];
    }
    if (t == 1023) off[N_NODES] = lds[1023];
}

// ---------------- hot path ----------------

// k-SPLIT edge kernel, take 2. Block = 4 waves = 2 groups of 64 edges; waves
// (2g,2g+1) split the k-loop. CRITICAL FIX vs R5: `half` is forced into an
// SGPR via readfirstlane, and each branch has compile-time-constant loop
// bounds in UNIFORM control flow -> the Wb/AC addresses stay provably
// wave-uniform -> s_load through the scalar cache (R5's threadIdx-derived
// bounds demoted them to per-lane global_load_dword: 616us, VALUBusy 14%).
__global__ __launch_bounds__(256) void edge_ks_kernel(
    const float* __restrict__ xin,
    const int* __restrict__ src, const int* __restrict__ dst,
    const int* __restrict__ rank, const int* __restrict__ off,
    const float* __restrict__ eattr,
    const float* __restrict__ AC,
    const float* __restrict__ Wb, const float* __restrict__ bb,
    float* __restrict__ msg_buf)
{
    __shared__ float part[128][HID_C + 1];  // +1 pad -> at worst 2-way bank alias (free)
    const int tid  = threadIdx.x;
    const int wave = tid >> 6;
    const int lane = tid & 63;
    const int grp  = wave >> 1;
    // scalar (SGPR) copy of the wave's half-index: keeps downstream control
    // flow + weight addresses uniform under the compiler's uniformity analysis
    const int half = __builtin_amdgcn_readfirstlane(wave & 1);
    const int eloc = grp * 64 + lane;          // 0..127
    const int e    = blockIdx.x * 128 + eloc;  // N_EDGES = 6250*128 exactly

    const int s = src[e];
    const float a0 = eattr[e*3+0], a1 = eattr[e*3+1], a2 = eattr[e*3+2];

    int p = 0;
    if (half) p = off[dst[e]] + rank[e];  // issued early; needed only at store

    float xs[IN_C];
    {
        const float4* xp = (const float4*)(xin + (size_t)s * IN_C);
        float4 q0 = xp[0], q1 = xp[1], q2 = xp[2], q3 = xp[3];
        xs[0]=q0.x; xs[1]=q0.y; xs[2]=q0.z; xs[3]=q0.w;
        xs[4]=q1.x; xs[5]=q1.y; xs[6]=q1.z; xs[7]=q1.w;
        xs[8]=q2.x; xs[9]=q2.y; xs[10]=q2.z; xs[11]=q2.w;
        xs[12]=q3.x; xs[13]=q3.y; xs[14]=q3.z; xs[15]=q3.w;
    }

    float msg[HID_C];
    #pragma unroll
    for (int o = 0; o < HID_C; ++o) msg[o] = 0.f;

    if (half == 0) {
        // k in [0,13)
        #pragma unroll 1
        for (int k = 0; k < 13; ++k) {
            float A0 = AC[k*4+0], A1 = AC[k*4+1], A2 = AC[k*4+2], C = AC[k*4+3];
            float hk = fmaxf(fmaf(a2, A2, fmaf(a1, A1, fmaf(a0, A0, C))), 0.f);
            const float* Wrow = Wb + k * (IN_C*HID_C);
            #pragma unroll
            for (int i = 0; i < IN_C; ++i) {
                float ai = hk * xs[i];
                #pragma unroll
                for (int o = 0; o < HID_C; ++o)
                    msg[o] = fmaf(ai, Wrow[i*HID_C+o], msg[o]);
            }
        }
        #pragma unroll
        for (int o = 0; o < HID_C; ++o) part[eloc][o] = msg[o];
    } else {
        // bias term (one k-equivalent) + k in [13,25)
        #pragma unroll
        for (int i = 0; i < IN_C; ++i) {
            #pragma unroll
            for (int o = 0; o < HID_C; ++o)
                msg[o] = fmaf(xs[i], bb[i*HID_C+o], msg[o]);
        }
        #pragma unroll 1
        for (int k = 13; k < 25; ++k) {
            float A0 = AC[k*4+0], A1 = AC[k*4+1], A2 = AC[k*4+2], C = AC[k*4+3];
            float hk = fmaxf(fmaf(a2, A2, fmaf(a1, A1, fmaf(a0, A0, C))), 0.f);
            const float* Wrow = Wb + k * (IN_C*HID_C);
            #pragma unroll
            for (int i = 0; i < IN_C; ++i) {
                float ai = hk * xs[i];
                #pragma unroll
                for (int o = 0; o < HID_C; ++o)
                    msg[o] = fmaf(ai, Wrow[i*HID_C+o], msg[o]);
            }
        }
    }
    __syncthreads();   // single barrier in uniform control flow
    if (half) {
        #pragma unroll
        for (int o = 0; o < HID_C; ++o) msg[o] += part[eloc][o];
        float4* mp = (float4*)(msg_buf + (size_t)p * HID_C);
        mp[0] = make_float4(msg[0], msg[1], msg[2], msg[3]);
        mp[1] = make_float4(msg[4], msg[5], msg[6], msg[7]);
        mp[2] = make_float4(msg[8], msg[9], msg[10], msg[11]);
        mp[3] = make_float4(msg[12], msg[13], msg[14], msg[15]);
    }
}

// 16 threads per node (lane = out channel). Segment-sum msg_buf rows
// [off[n], off[n+1]) -> mean -> + x@root + bias -> ELU.
__global__ __launch_bounds__(256) void node_gather_kernel(
    const float* __restrict__ xin, const float* __restrict__ msg_buf,
    const int* __restrict__ off,
    const float* __restrict__ root, const float* __restrict__ bias,
    float* __restrict__ xout)
{
    int t = blockIdx.x * blockDim.x + threadIdx.x;
    int n = t >> 4;
    int o = t & 15;
    if (n >= N_NODES) return;
    int lo = off[n], hi = off[n+1];
    float inv = 1.f / fmaxf((float)(hi - lo), 1.f);

    float s0 = 0.f, s1 = 0.f, s2 = 0.f, s3 = 0.f;
    int r = lo;
    for (; r + 4 <= hi; r += 4) {
        s0 += msg_buf[(size_t)r     * HID_C + o];
        s1 += msg_buf[(size_t)(r+1) * HID_C + o];
        s2 += msg_buf[(size_t)(r+2) * HID_C + o];
        s3 += msg_buf[(size_t)(r+3) * HID_C + o];
    }
    for (; r < hi; ++r) s0 += msg_buf[(size_t)r * HID_C + o];
    float s = (s0 + s1) + (s2 + s3);

    float acc = fmaf(s, inv, bias[o]);
    const float* xr = xin + (size_t)n * IN_C;
    #pragma unroll
    for (int i = 0; i < IN_C; ++i)
        acc = fmaf(xr[i], root[i*HID_C+o], acc);
    xout[(size_t)n*HID_C + o] = acc > 0.f ? acc : (expf(acc) - 1.f);
}

// fused: global mean pool (batch sorted -> contiguous segments) + final linear
__global__ __launch_bounds__(64) void pool_final_kernel(
    const float* __restrict__ xin, const int* __restrict__ goff,
    const float* __restrict__ fcW, const float* __restrict__ fcb,
    float* __restrict__ out)
{
    __shared__ float part[4][HID_C];
    __shared__ float pooled[HID_C];
    int g = blockIdx.x;
    int t = threadIdx.x;
    int c = t & 15, sub = t >> 4;
    int lo = goff[g], hi = goff[g+1];
    float s = 0.f;
    for (int n = lo + sub; n < hi; n += 4)
        s += xin[(size_t)n*HID_C + c];
    part[sub][c] = s;
    __syncthreads();
    if (t < HID_C) {
        float v = (part[0][t] + part[1][t] + part[2][t] + part[3][t])
                  / fmaxf((float)(hi - lo), 1.f);
        pooled[t] = v;
    }
    __syncthreads();
    if (t < OUT_C) {
        float acc = fcb[t];
        #pragma unroll
        for (int i = 0; i < HID_C; ++i)
            acc = fmaf(pooled[i], fcW[i*OUT_C+t], acc);
        out[g*OUT_C + t] = acc;
    }
}

// ---------------- launch ----------------

extern "C" void kernel_launch(void* const* d_in, const int* in_sizes, int n_in,
                              void* d_out, int out_size, void* d_ws, size_t ws_size,
                              hipStream_t stream)
{
    const float* x     = (const float*)d_in[0];
    const int*   ei    = (const int*)d_in[1];
    const float* eattr = (const float*)d_in[2];
    const int*   batch = (const int*)d_in[3];
    const float* W1a   = (const float*)d_in[4];
    const float* b1a   = (const float*)d_in[5];
    const float* g1    = (const float*)d_in[6];
    const float* bt1   = (const float*)d_in[7];
    const float* m1    = (const float*)d_in[8];
    const float* v1    = (const float*)d_in[9];
    const float* W1b   = (const float*)d_in[10];
    const float* b1b   = (const float*)d_in[11];
    const float* root1 = (const float*)d_in[12];
    const float* bias1 = (const float*)d_in[13];
    const float* W2a   = (const float*)d_in[14];
    const float* b2a   = (const float*)d_in[15];
    const float* g2    = (const float*)d_in[16];
    const float* bt2   = (const float*)d_in[17];
    const float* m2    = (const float*)d_in[18];
    const float* v2    = (const float*)d_in[19];
    const float* W2b   = (const float*)d_in[20];
    const float* b2b   = (const float*)d_in[21];
    const float* root2 = (const float*)d_in[22];
    const float* bias2 = (const float*)d_in[23];
    const float* fcW   = (const float*)d_in[24];
    const float* fcb   = (const float*)d_in[25];

    const int* src = ei;
    const int* dst = ei + N_EDGES;

    float* ws   = (float*)d_ws;
    float* MSG  = ws;                          // 12,800,000 f
    float* X1   = ws + 12800000;               //    800,000 f
    float* X2   = ws + 13600000;               //    800,000 f
    int*   RANK = (int*)(ws + 14400000);       //    800,000 i
    int*   CNT  = (int*)(ws + 15200000);       //     50,000 i
    int*   OFF  = (int*)(ws + 15250000);       //     50,001 i (+pad)
    int*   GOFF = (int*)(ws + 15300096);       //        501 i (+pad)
    float* AC1  = ws + 15300608;               //        128 f
    float* AC2  = ws + 15300736;               //        128 f
    // total 15,300,864 f = 61.2 MB

    hipMemsetAsync(CNT, 0, N_NODES * sizeof(int), stream);
    prep_graph_kernel<<<3, 256, 0, stream>>>(W1a, b1a, g1, bt1, m1, v1,
                                             W2a, b2a, g2, bt2, m2, v2,
                                             batch, AC1, AC2, GOFF);
    rank_kernel<<<N_EDGES/256, 256, 0, stream>>>(dst, CNT, RANK);
    scan_kernel<<<1, 1024, 0, stream>>>(CNT, OFF);

    edge_ks_kernel<<<N_EDGES/128, 256, 0, stream>>>(x, src, dst, RANK, OFF,
                                                    eattr, AC1, W1b, b1b, MSG);
    node_gather_kernel<<<(N_NODES*16+255)/256, 256, 0, stream>>>(x, MSG, OFF,
                                                                 root1, bias1, X1);

    edge_ks_kernel<<<N_EDGES/128, 256, 0, stream>>>(X1, src, dst, RANK, OFF,
                                                    eattr, AC2, W2b, b2b, MSG);
    node_gather_kernel<<<(N_NODES*16+255)/256, 256, 0, stream>>>(X1, MSG, OFF,
                                                                 root2, bias2, X2);

    pool_final_kernel<<<N_GRAPHS, 64, 0, stream>>>(X2, GOFF, fcW, fcb, (float*)d_out);
}

// Round 7
// 403.031 us; speedup vs baseline: 3.5260x; 1.1831x over previous
//
#include <hip/hip_runtime.h>
#include <math.h>

#define N_NODES 50000
#define N_EDGES 800000
#define IN_C 16
#define HID_C 16
#define OUT_C 10
#define N_GRAPHS 500
#define EDGE_DIM 3
#define MLP_HID 25
#define BN_EPS 1e-5f

#define SCAN_NB ((N_NODES + 255) / 256)   // 196 blocks

// ---------------- small prep ----------------

// block 0: fold BN into edge-MLP layer-1 -> AC[k][4]={A0,A1,A2,C}
// all blocks: goff[g] = lower_bound(batch, g) (batch sorted)
__global__ __launch_bounds__(256) void prep_graph_kernel(
    const float* __restrict__ W1a, const float* __restrict__ b1a,
    const float* __restrict__ g1, const float* __restrict__ bt1,
    const float* __restrict__ m1, const float* __restrict__ v1,
    const float* __restrict__ W2a, const float* __restrict__ b2a,
    const float* __restrict__ g2, const float* __restrict__ bt2,
    const float* __restrict__ m2, const float* __restrict__ v2,
    const int* __restrict__ batch,
    float* __restrict__ AC1, float* __restrict__ AC2,
    int* __restrict__ goff)
{
    int t = threadIdx.x;
    if (blockIdx.x == 0) {
        if (t < MLP_HID) {
            int k = t;
            float sc = g1[k] / sqrtf(v1[k] + BN_EPS);
            AC1[k*4+0] = sc * W1a[0*MLP_HID+k];
            AC1[k*4+1] = sc * W1a[1*MLP_HID+k];
            AC1[k*4+2] = sc * W1a[2*MLP_HID+k];
            AC1[k*4+3] = sc * (b1a[k] - m1[k]) + bt1[k];
        } else if (t >= 32 && t < 32 + MLP_HID) {
            int k = t - 32;
            float sc = g2[k] / sqrtf(v2[k] + BN_EPS);
            AC2[k*4+0] = sc * W2a[0*MLP_HID+k];
            AC2[k*4+1] = sc * W2a[1*MLP_HID+k];
            AC2[k*4+2] = sc * W2a[2*MLP_HID+k];
            AC2[k*4+3] = sc * (b2a[k] - m2[k]) + bt2[k];
        }
    }
    int g = blockIdx.x * blockDim.x + t;
    if (g <= N_GRAPHS) {
        int lo = 0, hi = N_NODES;
        while (lo < hi) {
            int mid = (lo + hi) >> 1;
            if (batch[mid] < g) lo = mid + 1; else hi = mid;
        }
        goff[g] = lo;
    }
}

// ---------------- CSR build (one atomic pass + parallel scan) ----------------

// rank[e] = arrival rank of edge e within its dst bucket; cnt ends as degree.
__global__ __launch_bounds__(256) void rank_kernel(const int* __restrict__ dst,
                                                   int* __restrict__ cnt,
                                                   int* __restrict__ rank) {
    int e = blockIdx.x * blockDim.x + threadIdx.x;
    if (e < N_EDGES) rank[e] = atomicAdd(&cnt[dst[e]], 1);
}

// phase 1: per-block sums of cnt (coalesced)
__global__ __launch_bounds__(256) void scan_p1(const int* __restrict__ cnt,
                                               int* __restrict__ bsum) {
    __shared__ int lds[256];
    int t = threadIdx.x;
    int idx = blockIdx.x * 256 + t;
    lds[t] = (idx < N_NODES) ? cnt[idx] : 0;
    __syncthreads();
    for (int d = 128; d > 0; d >>= 1) {
        if (t < d) lds[t] += lds[t + d];
        __syncthreads();
    }
    if (t == 0) bsum[blockIdx.x] = lds[0];
}

// phase 2: single small block scans the 196 block sums -> bpre (exclusive), total
__global__ __launch_bounds__(256) void scan_p2(const int* __restrict__ bsum,
                                               int* __restrict__ bpre,
                                               int* __restrict__ off) {
    __shared__ int lds[256];
    int t = threadIdx.x;
    lds[t] = (t < SCAN_NB) ? bsum[t] : 0;
    __syncthreads();
    for (int d = 1; d < 256; d <<= 1) {
        int v = (t >= d) ? lds[t - d] : 0;
        __syncthreads();
        lds[t] += v;
        __syncthreads();
    }
    if (t < SCAN_NB) bpre[t] = (t > 0) ? lds[t - 1] : 0;
    if (t == 255) off[N_NODES] = lds[255];   // total (== lds[SCAN_NB-1])
}

// phase 3: per-block exclusive scan + block prefix -> off (coalesced)
__global__ __launch_bounds__(256) void scan_p3(const int* __restrict__ cnt,
                                               const int* __restrict__ bpre,
                                               int* __restrict__ off) {
    __shared__ int lds[256];
    int t = threadIdx.x;
    int idx = blockIdx.x * 256 + t;
    int v = (idx < N_NODES) ? cnt[idx] : 0;
    lds[t] = v;
    __syncthreads();
    for (int d = 1; d < 256; d <<= 1) {
        int u = (t >= d) ? lds[t - d] : 0;
        __syncthreads();
        lds[t] += u;
        __syncthreads();
    }
    if (idx < N_NODES) off[idx] = bpre[blockIdx.x] + lds[t] - v;  // exclusive
}

// ---------------- hot path ----------------

// k-SPLIT edge kernel (verified R6 structure). Block = 4 waves = 2 groups of
// 64 edges; waves (2g,2g+1) split the k-loop. `half` forced into an SGPR via
// readfirstlane + compile-time loop bounds -> Wb/AC stay on the s_load path.
// unroll 2: gives the scheduler a second SGPR set to pipeline next
// iteration's s_loads under current FMAs.
__global__ __launch_bounds__(256) void edge_ks_kernel(
    const float* __restrict__ xin,
    const int* __restrict__ src, const int* __restrict__ dst,
    const int* __restrict__ rank, const int* __restrict__ off,
    const float* __restrict__ eattr,
    const float* __restrict__ AC,
    const float* __restrict__ Wb, const float* __restrict__ bb,
    float* __restrict__ msg_buf)
{
    __shared__ float part[128][HID_C + 1];
    const int tid  = threadIdx.x;
    const int wave = tid >> 6;
    const int lane = tid & 63;
    const int grp  = wave >> 1;
    const int half = __builtin_amdgcn_readfirstlane(wave & 1);
    const int eloc = grp * 64 + lane;          // 0..127
    const int e    = blockIdx.x * 128 + eloc;  // N_EDGES = 6250*128 exactly

    const int s = src[e];
    const float a0 = eattr[e*3+0], a1 = eattr[e*3+1], a2 = eattr[e*3+2];

    int p = 0;
    if (half) p = off[dst[e]] + rank[e];  // issued early; needed only at store

    float xs[IN_C];
    {
        const float4* xp = (const float4*)(xin + (size_t)s * IN_C);
        float4 q0 = xp[0], q1 = xp[1], q2 = xp[2], q3 = xp[3];
        xs[0]=q0.x; xs[1]=q0.y; xs[2]=q0.z; xs[3]=q0.w;
        xs[4]=q1.x; xs[5]=q1.y; xs[6]=q1.z; xs[7]=q1.w;
        xs[8]=q2.x; xs[9]=q2.y; xs[10]=q2.z; xs[11]=q2.w;
        xs[12]=q3.x; xs[13]=q3.y; xs[14]=q3.z; xs[15]=q3.w;
    }

    float msg[HID_C];
    #pragma unroll
    for (int o = 0; o < HID_C; ++o) msg[o] = 0.f;

    if (half == 0) {
        // k in [0,13)
        #pragma unroll 2
        for (int k = 0; k < 13; ++k) {
            float A0 = AC[k*4+0], A1 = AC[k*4+1], A2 = AC[k*4+2], C = AC[k*4+3];
            float hk = fmaxf(fmaf(a2, A2, fmaf(a1, A1, fmaf(a0, A0, C))), 0.f);
            const float* Wrow = Wb + k * (IN_C*HID_C);
            #pragma unroll
            for (int i = 0; i < IN_C; ++i) {
                float ai = hk * xs[i];
                #pragma unroll
                for (int o = 0; o < HID_C; ++o)
                    msg[o] = fmaf(ai, Wrow[i*HID_C+o], msg[o]);
            }
        }
        #pragma unroll
        for (int o = 0; o < HID_C; ++o) part[eloc][o] = msg[o];
    } else {
        // bias term (one k-equivalent) + k in [13,25)
        #pragma unroll
        for (int i = 0; i < IN_C; ++i) {
            #pragma unroll
            for (int o = 0; o < HID_C; ++o)
                msg[o] = fmaf(xs[i], bb[i*HID_C+o], msg[o]);
        }
        #pragma unroll 2
        for (int k = 13; k < 25; ++k) {
            float A0 = AC[k*4+0], A1 = AC[k*4+1], A2 = AC[k*4+2], C = AC[k*4+3];
            float hk = fmaxf(fmaf(a2, A2, fmaf(a1, A1, fmaf(a0, A0, C))), 0.f);
            const float* Wrow = Wb + k * (IN_C*HID_C);
            #pragma unroll
            for (int i = 0; i < IN_C; ++i) {
                float ai = hk * xs[i];
                #pragma unroll
                for (int o = 0; o < HID_C; ++o)
                    msg[o] = fmaf(ai, Wrow[i*HID_C+o], msg[o]);
            }
        }
    }
    __syncthreads();   // single barrier in uniform control flow
    if (half) {
        #pragma unroll
        for (int o = 0; o < HID_C; ++o) msg[o] += part[eloc][o];
        float4* mp = (float4*)(msg_buf + (size_t)p * HID_C);
        mp[0] = make_float4(msg[0], msg[1], msg[2], msg[3]);
        mp[1] = make_float4(msg[4], msg[5], msg[6], msg[7]);
        mp[2] = make_float4(msg[8], msg[9], msg[10], msg[11]);
        mp[3] = make_float4(msg[12], msg[13], msg[14], msg[15]);
    }
}

// 16 threads per node (lane = out channel). Segment-sum msg_buf rows
// [off[n], off[n+1]) -> mean -> + x@root + bias -> ELU.
__global__ __launch_bounds__(256) void node_gather_kernel(
    const float* __restrict__ xin, const float* __restrict__ msg_buf,
    const int* __restrict__ off,
    const float* __restrict__ root, const float* __restrict__ bias,
    float* __restrict__ xout)
{
    int t = blockIdx.x * blockDim.x + threadIdx.x;
    int n = t >> 4;
    int o = t & 15;
    if (n >= N_NODES) return;
    int lo = off[n], hi = off[n+1];
    float inv = 1.f / fmaxf((float)(hi - lo), 1.f);

    float s0 = 0.f, s1 = 0.f, s2 = 0.f, s3 = 0.f;
    int r = lo;
    for (; r + 4 <= hi; r += 4) {
        s0 += msg_buf[(size_t)r     * HID_C + o];
        s1 += msg_buf[(size_t)(r+1) * HID_C + o];
        s2 += msg_buf[(size_t)(r+2) * HID_C + o];
        s3 += msg_buf[(size_t)(r+3) * HID_C + o];
    }
    for (; r < hi; ++r) s0 += msg_buf[(size_t)r * HID_C + o];
    float s = (s0 + s1) + (s2 + s3);

    float acc = fmaf(s, inv, bias[o]);
    const float* xr = xin + (size_t)n * IN_C;
    #pragma unroll
    for (int i = 0; i < IN_C; ++i)
        acc = fmaf(xr[i], root[i*HID_C+o], acc);
    xout[(size_t)n*HID_C + o] = acc > 0.f ? acc : (expf(acc) - 1.f);
}

// fused: global mean pool (batch sorted -> contiguous segments) + final linear
__global__ __launch_bounds__(64) void pool_final_kernel(
    const float* __restrict__ xin, const int* __restrict__ goff,
    const float* __restrict__ fcW, const float* __restrict__ fcb,
    float* __restrict__ out)
{
    __shared__ float part[4][HID_C];
    __shared__ float pooled[HID_C];
    int g = blockIdx.x;
    int t = threadIdx.x;
    int c = t & 15, sub = t >> 4;
    int lo = goff[g], hi = goff[g+1];
    float s = 0.f;
    for (int n = lo + sub; n < hi; n += 4)
        s += xin[(size_t)n*HID_C + c];
    part[sub][c] = s;
    __syncthreads();
    if (t < HID_C) {
        float v = (part[0][t] + part[1][t] + part[2][t] + part[3][t])
                  / fmaxf((float)(hi - lo), 1.f);
        pooled[t] = v;
    }
    __syncthreads();
    if (t < OUT_C) {
        float acc = fcb[t];
        #pragma unroll
        for (int i = 0; i < HID_C; ++i)
            acc = fmaf(pooled[i], fcW[i*OUT_C+t], acc);
        out[g*OUT_C + t] = acc;
    }
}

// ---------------- launch ----------------

extern "C" void kernel_launch(void* const* d_in, const int* in_sizes, int n_in,
                              void* d_out, int out_size, void* d_ws, size_t ws_size,
                              hipStream_t stream)
{
    const float* x     = (const float*)d_in[0];
    const int*   ei    = (const int*)d_in[1];
    const float* eattr = (const float*)d_in[2];
    const int*   batch = (const int*)d_in[3];
    const float* W1a   = (const float*)d_in[4];
    const float* b1a   = (const float*)d_in[5];
    const float* g1    = (const float*)d_in[6];
    const float* bt1   = (const float*)d_in[7];
    const float* m1    = (const float*)d_in[8];
    const float* v1    = (const float*)d_in[9];
    const float* W1b   = (const float*)d_in[10];
    const float* b1b   = (const float*)d_in[11];
    const float* root1 = (const float*)d_in[12];
    const float* bias1 = (const float*)d_in[13];
    const float* W2a   = (const float*)d_in[14];
    const float* b2a   = (const float*)d_in[15];
    const float* g2    = (const float*)d_in[16];
    const float* bt2   = (const float*)d_in[17];
    const float* m2    = (const float*)d_in[18];
    const float* v2    = (const float*)d_in[19];
    const float* W2b   = (const float*)d_in[20];
    const float* b2b   = (const float*)d_in[21];
    const float* root2 = (const float*)d_in[22];
    const float* bias2 = (const float*)d_in[23];
    const float* fcW   = (const float*)d_in[24];
    const float* fcb   = (const float*)d_in[25];

    const int* src = ei;
    const int* dst = ei + N_EDGES;

    float* ws   = (float*)d_ws;
    float* MSG  = ws;                          // 12,800,000 f
    float* X1   = ws + 12800000;               //    800,000 f
    float* X2   = ws + 13600000;               //    800,000 f
    int*   RANK = (int*)(ws + 14400000);       //    800,000 i
    int*   CNT  = (int*)(ws + 15200000);       //     50,000 i
    int*   OFF  = (int*)(ws + 15250000);       //     50,001 i (+pad)
    int*   GOFF = (int*)(ws + 15300096);       //        501 i (+pad)
    int*   BSUM = (int*)(ws + 15300608);       //        196 i (+pad)
    int*   BPRE = (int*)(ws + 15300864);       //        196 i (+pad)
    float* AC1  = ws + 15301120;               //        128 f
    float* AC2  = ws + 15301248;               //        128 f
    // total 15,301,376 f = 61.2 MB

    hipMemsetAsync(CNT, 0, N_NODES * sizeof(int), stream);
    prep_graph_kernel<<<3, 256, 0, stream>>>(W1a, b1a, g1, bt1, m1, v1,
                                             W2a, b2a, g2, bt2, m2, v2,
                                             batch, AC1, AC2, GOFF);
    rank_kernel<<<N_EDGES/256, 256, 0, stream>>>(dst, CNT, RANK);
    scan_p1<<<SCAN_NB, 256, 0, stream>>>(CNT, BSUM);
    scan_p2<<<1, 256, 0, stream>>>(BSUM, BPRE, OFF);
    scan_p3<<<SCAN_NB, 256, 0, stream>>>(CNT, BPRE, OFF);

    edge_ks_kernel<<<N_EDGES/128, 256, 0, stream>>>(x, src, dst, RANK, OFF,
                                                    eattr, AC1, W1b, b1b, MSG);
    node_gather_kernel<<<(N_NODES*16+255)/256, 256, 0, stream>>>(x, MSG, OFF,
                                                                 root1, bias1, X1);

    edge_ks_kernel<<<N_EDGES/128, 256, 0, stream>>>(X1, src, dst, RANK, OFF,
                                                    eattr, AC2, W2b, b2b, MSG);
    node_gather_kernel<<<(N_NODES*16+255)/256, 256, 0, stream>>>(X1, MSG, OFF,
                                                                 root2, bias2, X2);

    pool_final_kernel<<<N_GRAPHS, 64, 0, stream>>>(X2, GOFF, fcW, fcb, (float*)d_out);
}

// Round 8
// 309.906 us; speedup vs baseline: 4.5856x; 1.3005x over previous
//
#include <hip/hip_runtime.h>
#include <math.h>

#define N_NODES 50000
#define N_EDGES 800000
#define IN_C 16
#define HID_C 16
#define OUT_C 10
#define N_GRAPHS 500
#define EDGE_DIM 3
#define MLP_HID 25
#define BN_EPS 1e-5f

#define SCAN_NB ((N_NODES + 255) / 256)   // 196 blocks

typedef __attribute__((ext_vector_type(8))) short short8;
typedef __attribute__((ext_vector_type(4))) float f32x4;
union U4S8 { uint4 u; short8 s; };

// ---------------- small prep ----------------

// block 0: fold BN into edge-MLP layer-1 -> AC[k][4]={A0,A1,A2,C}, k<25;
// AC[25]={0,0,0,1} so the bias rows of W' get h==relu(1)==1.
// all blocks: goff[g] = lower_bound(batch, g) (batch sorted)
__global__ __launch_bounds__(256) void prep_graph_kernel(
    const float* __restrict__ W1a, const float* __restrict__ b1a,
    const float* __restrict__ g1, const float* __restrict__ bt1,
    const float* __restrict__ m1, const float* __restrict__ v1,
    const float* __restrict__ W2a, const float* __restrict__ b2a,
    const float* __restrict__ g2, const float* __restrict__ bt2,
    const float* __restrict__ m2, const float* __restrict__ v2,
    const int* __restrict__ batch,
    float* __restrict__ AC1, float* __restrict__ AC2,
    int* __restrict__ goff)
{
    int t = threadIdx.x;
    if (blockIdx.x == 0) {
        if (t < 26) {
            int k = t;
            if (k < 25) {
                float sc = g1[k] / sqrtf(v1[k] + BN_EPS);
                AC1[k*4+0] = sc * W1a[0*MLP_HID+k];
                AC1[k*4+1] = sc * W1a[1*MLP_HID+k];
                AC1[k*4+2] = sc * W1a[2*MLP_HID+k];
                AC1[k*4+3] = sc * (b1a[k] - m1[k]) + bt1[k];
            } else {
                AC1[100] = 0.f; AC1[101] = 0.f; AC1[102] = 0.f; AC1[103] = 1.f;
            }
        } else if (t >= 32 && t < 58) {
            int k = t - 32;
            if (k < 25) {
                float sc = g2[k] / sqrtf(v2[k] + BN_EPS);
                AC2[k*4+0] = sc * W2a[0*MLP_HID+k];
                AC2[k*4+1] = sc * W2a[1*MLP_HID+k];
                AC2[k*4+2] = sc * W2a[2*MLP_HID+k];
                AC2[k*4+3] = sc * (b2a[k] - m2[k]) + bt2[k];
            } else {
                AC2[100] = 0.f; AC2[101] = 0.f; AC2[102] = 0.f; AC2[103] = 1.f;
            }
        }
    }
    int g = blockIdx.x * blockDim.x + t;
    if (g <= N_GRAPHS) {
        int lo = 0, hi = N_NODES;
        while (lo < hi) {
            int mid = (lo + hi) >> 1;
            if (batch[mid] < g) lo = mid + 1; else hi = mid;
        }
        goff[g] = lo;
    }
}

// Pack W' = [Wb rows (k'=k*16+i, k<25) ; bb rows (k'=400+i)] (416 x 16) into
// per-MFMA per-lane B-fragments, split hi/lo bf16 (Markidis: removes the
// systematic bf16 W-rounding error). Element j of (m, lane L): row
// k' = 32m + 8(L>>4) + j, col o = L&15. 2 layers x 13 m x 64 lanes.
__global__ __launch_bounds__(256) void pack_w_kernel(
    const float* __restrict__ W1b, const float* __restrict__ b1b,
    const float* __restrict__ W2b, const float* __restrict__ b2b,
    unsigned int* __restrict__ WHI1, unsigned int* __restrict__ WLO1,
    unsigned int* __restrict__ WHI2, unsigned int* __restrict__ WLO2)
{
    int t = blockIdx.x * 256 + threadIdx.x;
    if (t >= 1664) return;
    const float *Wb, *bb; unsigned int *WH, *WL;
    int tl = t;
    if (t < 832) { Wb = W1b; bb = b1b; WH = WHI1; WL = WLO1; }
    else { tl = t - 832; Wb = W2b; bb = b2b; WH = WHI2; WL = WLO2; }
    int m = tl >> 6;
    int L = tl & 63;
    int q = L >> 4, o = L & 15;
    unsigned int hi[8], lo[8];
    for (int j = 0; j < 8; ++j) {
        int kp = m*32 + q*8 + j;          // 0..415
        int k = kp >> 4, i = kp & 15;
        float w = (k < 25) ? Wb[k*256 + i*16 + o] : bb[i*16 + o];
        unsigned int u = __float_as_uint(w);
        unsigned int h = (u + 0x7FFFu + ((u >> 16) & 1u)) >> 16;   // bf16 RNE
        hi[j] = h;
        float rl = w - __uint_as_float(h << 16);
        unsigned int ul = __float_as_uint(rl);
        lo[j] = (ul + 0x7FFFu + ((ul >> 16) & 1u)) >> 16;
    }
    int base = (m*64 + L) * 4;
    for (int d = 0; d < 4; ++d) {
        WH[base + d] = hi[2*d] | (hi[2*d+1] << 16);
        WL[base + d] = lo[2*d] | (lo[2*d+1] << 16);
    }
}

// ---------------- CSR build (one atomic pass + parallel scan) ----------------

__global__ __launch_bounds__(256) void rank_kernel(const int* __restrict__ dst,
                                                   int* __restrict__ cnt,
                                                   int* __restrict__ rank) {
    int e = blockIdx.x * blockDim.x + threadIdx.x;
    if (e < N_EDGES) rank[e] = atomicAdd(&cnt[dst[e]], 1);
}

__global__ __launch_bounds__(256) void scan_p1(const int* __restrict__ cnt,
                                               int* __restrict__ bsum) {
    __shared__ int lds[256];
    int t = threadIdx.x;
    int idx = blockIdx.x * 256 + t;
    lds[t] = (idx < N_NODES) ? cnt[idx] : 0;
    __syncthreads();
    for (int d = 128; d > 0; d >>= 1) {
        if (t < d) lds[t] += lds[t + d];
        __syncthreads();
    }
    if (t == 0) bsum[blockIdx.x] = lds[0];
}

__global__ __launch_bounds__(256) void scan_p2(const int* __restrict__ bsum,
                                               int* __restrict__ bpre,
                                               int* __restrict__ off) {
    __shared__ int lds[256];
    int t = threadIdx.x;
    lds[t] = (t < SCAN_NB) ? bsum[t] : 0;
    __syncthreads();
    for (int d = 1; d < 256; d <<= 1) {
        int v = (t >= d) ? lds[t - d] : 0;
        __syncthreads();
        lds[t] += v;
        __syncthreads();
    }
    if (t < SCAN_NB) bpre[t] = (t > 0) ? lds[t - 1] : 0;
    if (t == 255) off[N_NODES] = lds[255];
}

__global__ __launch_bounds__(256) void scan_p3(const int* __restrict__ cnt,
                                               const int* __restrict__ bpre,
                                               int* __restrict__ off) {
    __shared__ int lds[256];
    int t = threadIdx.x;
    int idx = blockIdx.x * 256 + t;
    int v = (idx < N_NODES) ? cnt[idx] : 0;
    lds[t] = v;
    __syncthreads();
    for (int d = 1; d < 256; d <<= 1) {
        int u = (t >= d) ? lds[t - d] : 0;
        __syncthreads();
        lds[t] += u;
        __syncthreads();
    }
    if (idx < N_NODES) off[idx] = bpre[blockIdx.x] + lds[t] - v;
}

// ---------------- hot path: MFMA edge kernel ----------------

// Per wave: 16 edges. msg[16e x 16o] = H[16e x 416] @ W'[416 x 16o] via
// 13 x mfma_f32_16x16x32_bf16 (x2 for the W_lo split, chained into the same
// fp32 accumulator). H[e][k'] = h[e][k'>>4] * xs[e][k'&15] is formed on the
// fly: A-fragment lane L holds A[e=L&15][k'=32m+8q+j], so each lane serves
// one edge and exactly one k per MFMA (k=2m+(q>>1)), with a fixed 8-wide
// i-slice of xs (i0=(q&1)*8). bf16 pack = 1 v_perm (truncation; error is
// per-edge random -> averages out downstream). No barriers after the block
// preamble: all staging is wave-private LDS.
__global__ __launch_bounds__(256) void edge_mfma_kernel(
    const float* __restrict__ xin,
    const int* __restrict__ src, const int* __restrict__ dst,
    const int* __restrict__ rank, const int* __restrict__ off,
    const float* __restrict__ eattr,
    const float* __restrict__ AC,
    const unsigned int* __restrict__ WHI, const unsigned int* __restrict__ WLO,
    float* __restrict__ msg_buf)
{
    __shared__ uint4 wlo_s[832];                         // 13312 B
    __shared__ float ac_s[104];                          //   416 B
    __shared__ __attribute__((aligned(16))) float xs_s[4][16][16];  // 4096 B
    __shared__ __attribute__((aligned(16))) float ea_s[4][16][4];   // 1024 B
    __shared__ int   pp_s[4][16];                        //   256 B

    const int tid = threadIdx.x;
    // block preamble: stage W_lo fragments + AC into LDS
    #pragma unroll
    for (int it = 0; it < 4; ++it) {
        int gi = tid + it*256;
        if (gi < 832) wlo_s[gi] = ((const uint4*)WLO)[gi];
    }
    if (tid < 104) ac_s[tid] = AC[tid];
    __syncthreads();

    const int wave = tid >> 6;
    const int lane = tid & 63;
    const int q = lane >> 4;

    // per-wave stationary W_hi fragments (13 x 4 VGPRs)
    short8 whi[13];
    #pragma unroll
    for (int m = 0; m < 13; ++m) {
        U4S8 c; c.u = ((const uint4*)WHI)[m*64 + lane];
        whi[m] = c.s;
    }

    const int tile = blockIdx.x * 4 + wave;   // 50000 tiles of 16 edges
    const int e0 = tile * 16;

    // wave-private staging: xs rows, edge attrs, CSR slots
    {
        int el = lane >> 2, part = lane & 3;
        int s = src[e0 + el];
        const float4 v = ((const float4*)(xin + (size_t)s * IN_C))[part];
        *(float4*)&xs_s[wave][el][part*4] = v;
    }
    if (lane < 48) {
        int c = lane >> 4, e = lane & 15;
        ea_s[wave][e][c] = eattr[(size_t)(e0 + e)*3 + c];
    }
    if (lane < 16) {
        int e = e0 + lane;
        pp_s[wave][lane] = off[dst[e]] + rank[e];
    }
    // same-wave LDS RAW: compiler inserts lgkmcnt waits; no barrier needed.

    const int e = lane & 15;
    const int i0 = (q & 1) * 8;
    const float4 ea = *(const float4*)&ea_s[wave][e][0];
    const float a0 = ea.x, a1 = ea.y, a2 = ea.z;
    float x8[8];
    {
        float4 v0 = *(const float4*)&xs_s[wave][e][i0];
        float4 v1 = *(const float4*)&xs_s[wave][e][i0 + 4];
        x8[0]=v0.x; x8[1]=v0.y; x8[2]=v0.z; x8[3]=v0.w;
        x8[4]=v1.x; x8[5]=v1.y; x8[6]=v1.z; x8[7]=v1.w;
    }

    f32x4 acc = {0.f, 0.f, 0.f, 0.f};
    #pragma unroll
    for (int m = 0; m < 13; ++m) {
        int k = 2*m + (q >> 1);
        const float4 A = *(const float4*)&ac_s[k*4];
        float hk = fmaxf(fmaf(a2, A.z, fmaf(a1, A.y, fmaf(a0, A.x, A.w))), 0.f);
        unsigned int pd0, pd1, pd2, pd3;
        {
            unsigned int b0 = __float_as_uint(hk * x8[0]);
            unsigned int b1 = __float_as_uint(hk * x8[1]);
            pd0 = __builtin_amdgcn_perm(b1, b0, 0x07060302u);
            unsigned int b2 = __float_as_uint(hk * x8[2]);
            unsigned int b3 = __float_as_uint(hk * x8[3]);
            pd1 = __builtin_amdgcn_perm(b3, b2, 0x07060302u);
            unsigned int b4 = __float_as_uint(hk * x8[4]);
            unsigned int b5 = __float_as_uint(hk * x8[5]);
            pd2 = __builtin_amdgcn_perm(b5, b4, 0x07060302u);
            unsigned int b6 = __float_as_uint(hk * x8[6]);
            unsigned int b7 = __float_as_uint(hk * x8[7]);
            pd3 = __builtin_amdgcn_perm(b7, b6, 0x07060302u);
        }
        U4S8 af; af.u = make_uint4(pd0, pd1, pd2, pd3);
        U4S8 wl; wl.u = wlo_s[m*64 + lane];
        acc = __builtin_amdgcn_mfma_f32_16x16x32_bf16(af.s, whi[m], acc, 0, 0, 0);
        acc = __builtin_amdgcn_mfma_f32_16x16x32_bf16(af.s, wl.s,   acc, 0, 0, 0);
    }

    // D layout: col(o) = lane&15, row(edge) = q*4 + r
    const int o = lane & 15;
    #pragma unroll
    for (int r = 0; r < 4; ++r) {
        int p = pp_s[wave][q*4 + r];
        msg_buf[(size_t)p * HID_C + o] = acc[r];
    }
}

// 16 threads per node (lane = out channel). Segment-sum msg_buf rows
// [off[n], off[n+1]) -> mean -> + x@root + bias -> ELU.
__global__ __launch_bounds__(256) void node_gather_kernel(
    const float* __restrict__ xin, const float* __restrict__ msg_buf,
    const int* __restrict__ off,
    const float* __restrict__ root, const float* __restrict__ bias,
    float* __restrict__ xout)
{
    int t = blockIdx.x * blockDim.x + threadIdx.x;
    int n = t >> 4;
    int o = t & 15;
    if (n >= N_NODES) return;
    int lo = off[n], hi = off[n+1];
    float inv = 1.f / fmaxf((float)(hi - lo), 1.f);

    float s0 = 0.f, s1 = 0.f, s2 = 0.f, s3 = 0.f;
    int r = lo;
    for (; r + 4 <= hi; r += 4) {
        s0 += msg_buf[(size_t)r     * HID_C + o];
        s1 += msg_buf[(size_t)(r+1) * HID_C + o];
        s2 += msg_buf[(size_t)(r+2) * HID_C + o];
        s3 += msg_buf[(size_t)(r+3) * HID_C + o];
    }
    for (; r < hi; ++r) s0 += msg_buf[(size_t)r * HID_C + o];
    float s = (s0 + s1) + (s2 + s3);

    float acc = fmaf(s, inv, bias[o]);
    const float* xr = xin + (size_t)n * IN_C;
    #pragma unroll
    for (int i = 0; i < IN_C; ++i)
        acc = fmaf(xr[i], root[i*HID_C+o], acc);
    xout[(size_t)n*HID_C + o] = acc > 0.f ? acc : (expf(acc) - 1.f);
}

// fused: global mean pool (batch sorted -> contiguous segments) + final linear
__global__ __launch_bounds__(64) void pool_final_kernel(
    const float* __restrict__ xin, const int* __restrict__ goff,
    const float* __restrict__ fcW, const float* __restrict__ fcb,
    float* __restrict__ out)
{
    __shared__ float part[4][HID_C];
    __shared__ float pooled[HID_C];
    int g = blockIdx.x;
    int t = threadIdx.x;
    int c = t & 15, sub = t >> 4;
    int lo = goff[g], hi = goff[g+1];
    float s = 0.f;
    for (int n = lo + sub; n < hi; n += 4)
        s += xin[(size_t)n*HID_C + c];
    part[sub][c] = s;
    __syncthreads();
    if (t < HID_C) {
        pooled[t] = (part[0][t] + part[1][t] + part[2][t] + part[3][t])
                    / fmaxf((float)(hi - lo), 1.f);
    }
    __syncthreads();
    if (t < OUT_C) {
        float acc = fcb[t];
        #pragma unroll
        for (int i = 0; i < HID_C; ++i)
            acc = fmaf(pooled[i], fcW[i*OUT_C+t], acc);
        out[g*OUT_C + t] = acc;
    }
}

// ---------------- launch ----------------

extern "C" void kernel_launch(void* const* d_in, const int* in_sizes, int n_in,
                              void* d_out, int out_size, void* d_ws, size_t ws_size,
                              hipStream_t stream)
{
    const float* x     = (const float*)d_in[0];
    const int*   ei    = (const int*)d_in[1];
    const float* eattr = (const float*)d_in[2];
    const int*   batch = (const int*)d_in[3];
    const float* W1a   = (const float*)d_in[4];
    const float* b1a   = (const float*)d_in[5];
    const float* g1    = (const float*)d_in[6];
    const float* bt1   = (const float*)d_in[7];
    const float* m1    = (const float*)d_in[8];
    const float* v1    = (const float*)d_in[9];
    const float* W1b   = (const float*)d_in[10];
    const float* b1b   = (const float*)d_in[11];
    const float* root1 = (const float*)d_in[12];
    const float* bias1 = (const float*)d_in[13];
    const float* W2a   = (const float*)d_in[14];
    const float* b2a   = (const float*)d_in[15];
    const float* g2    = (const float*)d_in[16];
    const float* bt2   = (const float*)d_in[17];
    const float* m2    = (const float*)d_in[18];
    const float* v2    = (const float*)d_in[19];
    const float* W2b   = (const float*)d_in[20];
    const float* b2b   = (const float*)d_in[21];
    const float* root2 = (const float*)d_in[22];
    const float* bias2 = (const float*)d_in[23];
    const float* fcW   = (const float*)d_in[24];
    const float* fcb   = (const float*)d_in[25];

    const int* src = ei;
    const int* dst = ei + N_EDGES;

    float* ws   = (float*)d_ws;
    float* MSG  = ws;                                   // 12,800,000 f
    float* X1   = ws + 12800000;                        //    800,000 f
    float* X2   = ws + 13600000;                        //    800,000 f
    int*   RANK = (int*)(ws + 14400000);                //    800,000 i
    int*   CNT  = (int*)(ws + 15200000);                //     50,000 i
    int*   OFF  = (int*)(ws + 15250000);                //     50,001 i (+pad)
    int*   GOFF = (int*)(ws + 15300064);                //        501 i (+pad)
    unsigned int* WHI1 = (unsigned int*)(ws + 15300576);//      3,328 u (16B aligned)
    unsigned int* WLO1 = (unsigned int*)(ws + 15303904);//      3,328 u
    unsigned int* WHI2 = (unsigned int*)(ws + 15307232);//      3,328 u
    unsigned int* WLO2 = (unsigned int*)(ws + 15310560);//      3,328 u
    float* AC1  = ws + 15313888;                        //        104 f (+pad)
    float* AC2  = ws + 15314000;                        //        104 f
    int*   BSUM = (int*)(ws + 15314112);                //        196 i (+pad)
    int*   BPRE = (int*)(ws + 15314368);                //        196 i
    // total ~15,314,564 f = 61.26 MB

    hipMemsetAsync(CNT, 0, N_NODES * sizeof(int), stream);
    prep_graph_kernel<<<3, 256, 0, stream>>>(W1a, b1a, g1, bt1, m1, v1,
                                             W2a, b2a, g2, bt2, m2, v2,
                                             batch, AC1, AC2, GOFF);
    pack_w_kernel<<<7, 256, 0, stream>>>(W1b, b1b, W2b, b2b,
                                         WHI1, WLO1, WHI2, WLO2);
    rank_kernel<<<N_EDGES/256, 256, 0, stream>>>(dst, CNT, RANK);
    scan_p1<<<SCAN_NB, 256, 0, stream>>>(CNT, BSUM);
    scan_p2<<<1, 256, 0, stream>>>(BSUM, BPRE, OFF);
    scan_p3<<<SCAN_NB, 256, 0, stream>>>(CNT, BPRE, OFF);

    edge_mfma_kernel<<<N_EDGES/64, 256, 0, stream>>>(x, src, dst, RANK, OFF,
                                                     eattr, AC1, WHI1, WLO1, MSG);
    node_gather_kernel<<<(N_NODES*16+255)/256, 256, 0, stream>>>(x, MSG, OFF,
                                                                 root1, bias1, X1);

    edge_mfma_kernel<<<N_EDGES/64, 256, 0, stream>>>(X1, src, dst, RANK, OFF,
                                                     eattr, AC2, WHI2, WLO2, MSG);
    node_gather_kernel<<<(N_NODES*16+255)/256, 256, 0, stream>>>(X1, MSG, OFF,
                                                                 root2, bias2, X2);

    pool_final_kernel<<<N_GRAPHS, 64, 0, stream>>>(X2, GOFF, fcW, fcb, (float*)d_out);
}